// Round 8
// baseline (5485.537 us; speedup 1.0000x reference)
//
#include <hip/hip_runtime.h>
#include <hip/hip_cooperative_groups.h>

#define N_NODES 32768
#define DEG 16
#define IN_F 128
#define HIDF 256
#define N_GRAPHS 256
#define NPG 128
#define OUT_F 16

namespace cgn = cooperative_groups;

typedef unsigned short u16;
typedef unsigned int u32;
typedef __bf16 bf16x8 __attribute__((ext_vector_type(8)));
typedef float f32x4 __attribute__((ext_vector_type(4)));
typedef u16 u16x4 __attribute__((ext_vector_type(4)));
typedef u16 u16x8 __attribute__((ext_vector_type(8)));

__device__ __forceinline__ u16 f2bf(float f) {
  union { float f; unsigned u; } v; v.f = f;
  return (u16)((v.u + 0x7FFFu + ((v.u >> 16) & 1u)) >> 16);
}
__device__ __forceinline__ float bf2f(u16 b) {
  union { unsigned u; float f; } v; v.u = ((unsigned)b) << 16;
  return v.f;
}
__device__ __forceinline__ float sigm(float x) { return 1.0f / (1.0f + __expf(-x)); }
__device__ __forceinline__ float tanhfast(float x) {
  float e = __expf(2.0f * x);
  return (e - 1.0f) / (e + 1.0f);
}

// ---- prep kernels -------------------------------------------------------

__global__ void k_prep_x(const float* __restrict__ x, u16* __restrict__ out, int n4) {
  int i = blockIdx.x * blockDim.x + threadIdx.x;
  if (i < n4) {
    float4 v = ((const float4*)x)[i];
    ushort4 o;
    o.x = f2bf(v.x); o.y = f2bf(v.y); o.z = f2bf(v.z); o.w = f2bf(v.w);
    ((ushort4*)out)[i] = o;
  }
}

// Gate-interleaved weight rows: p = fe*4 + gate (gate order i,f,g,o).
// So a 16x16 MFMA C-fragment's j index (rows lq*4+j) IS the gate index.
__global__ void k_prep_wg(const float* __restrict__ Wi, const float* __restrict__ Wh,
                          const float* __restrict__ bi, const float* __restrict__ bh,
                          u16* __restrict__ Wip, u16* __restrict__ Whp,
                          float* __restrict__ bwp, int F) {
  int total = 4 * F * F;
  for (int idx = blockIdx.x * blockDim.x + threadIdx.x; idx < total;
       idx += gridDim.x * blockDim.x) {
    int p = idx / F, k = idx % F;
    int fe = p >> 2, g = p & 3;
    int orig = g * F + fe;
    Wip[idx] = f2bf(Wi[orig * F + k]);
    Whp[idx] = f2bf(Wh[orig * F + k]);
    if (k == 0) bwp[p] = bi[orig] + bh[orig];
  }
}

__global__ void k_prep_cast(const float* __restrict__ Ws, const float* __restrict__ Wn,
                            u16* __restrict__ Bs, u16* __restrict__ Bn, int n) {
  int i = blockIdx.x * blockDim.x + threadIdx.x;
  if (i < n) { Bs[i] = f2bf(Ws[i]); Bn[i] = f2bf(Wn[i]); }
}

// ---- dense GEMM: C[M][NC] = bf16(A[M][K] @ B[NC][K]^T + bias) ------------
template <int K, int NC>
__launch_bounds__(256, 4)
__global__ void k_gemm(const u16* __restrict__ A, const u16* __restrict__ B,
                       const float* __restrict__ bias, u16* __restrict__ C) {
  constexpr int ROWB = 2 * K;
  __shared__ u16 lds[64 * K];
  char* ldsb = (char*)lds;
  const int tid = threadIdx.x;
  const int w = tid >> 6;
  const int lane = tid & 63;
  const int l16 = lane & 15, lq = lane >> 4;
  const int row0 = blockIdx.x * 64;
  const int col0 = blockIdx.y * 128;

  constexpr int CH = K / 8;
  constexpr int RPI = 256 / CH;
#pragma unroll
  for (int it = 0; it < 64 / RPI; ++it) {
    int r = tid / CH + it * RPI;
    int ch = tid % CH;
    bf16x8 v = *(const bf16x8*)(A + (size_t)(row0 + r) * K + ch * 8);
    int bo = r * ROWB + ((ch * 16) ^ ((r & 7) << 4));
    *(bf16x8*)(ldsb + bo) = v;
  }
  __syncthreads();

  f32x4 acc[4][2];
#pragma unroll
  for (int mt = 0; mt < 4; ++mt)
#pragma unroll
    for (int nt = 0; nt < 2; ++nt)
#pragma unroll
      for (int j = 0; j < 4; ++j) acc[mt][nt][j] = 0.f;

  for (int ks = 0; ks < K / 32; ++ks) {
    bf16x8 a[4];
#pragma unroll
    for (int mt = 0; mt < 4; ++mt) {
      int r = mt * 16 + l16;
      int bo = r * ROWB + (((ks * 32 + lq * 8) * 2) ^ ((r & 7) << 4));
      a[mt] = *(const bf16x8*)(ldsb + bo);
    }
#pragma unroll
    for (int nt = 0; nt < 2; ++nt) {
      int coln = col0 + w * 32 + nt * 16 + l16;
      bf16x8 b = *(const bf16x8*)(B + (size_t)coln * K + ks * 32 + lq * 8);
#pragma unroll
      for (int mt = 0; mt < 4; ++mt)
        acc[mt][nt] = __builtin_amdgcn_mfma_f32_16x16x32_bf16(a[mt], b, acc[mt][nt], 0, 0, 0);
    }
  }
#pragma unroll
  for (int mt = 0; mt < 4; ++mt)
#pragma unroll
    for (int nt = 0; nt < 2; ++nt) {
      int coln = col0 + w * 32 + nt * 16 + l16;
      float bb = bias[coln];
#pragma unroll
      for (int j = 0; j < 4; ++j) {
        int r = row0 + mt * 16 + lq * 4 + j;
        C[(size_t)r * NC + coln] = f2bf(acc[mt][nt][j] + bb);
      }
    }
}

// ---- combine GEMM: C[r][coln] = relu_bf16(XS[r][coln] + A[r]@B[coln]) ----
template <int K>
__launch_bounds__(256, 4)
__global__ void k_comb(const u16* __restrict__ A, const u16* __restrict__ B,
                       const u16* __restrict__ XS, u16* __restrict__ C) {
  constexpr int ROWB = 2 * K;
  __shared__ u16 lds[64 * K];
  char* ldsb = (char*)lds;
  const int tid = threadIdx.x;
  const int w = tid >> 6;
  const int lane = tid & 63;
  const int l16 = lane & 15, lq = lane >> 4;
  const int row0 = blockIdx.x * 64;
  const int col0 = blockIdx.y * 128;

  constexpr int CH = K / 8;
  constexpr int RPI = 256 / CH;
#pragma unroll
  for (int it = 0; it < 64 / RPI; ++it) {
    int r = tid / CH + it * RPI;
    int ch = tid % CH;
    bf16x8 v = *(const bf16x8*)(A + (size_t)(row0 + r) * K + ch * 8);
    int bo = r * ROWB + ((ch * 16) ^ ((r & 7) << 4));
    *(bf16x8*)(ldsb + bo) = v;
  }
  __syncthreads();

  f32x4 acc[4][2];
#pragma unroll
  for (int mt = 0; mt < 4; ++mt)
#pragma unroll
    for (int nt = 0; nt < 2; ++nt)
#pragma unroll
      for (int j = 0; j < 4; ++j) acc[mt][nt][j] = 0.f;

  for (int ks = 0; ks < K / 32; ++ks) {
    bf16x8 a[4];
#pragma unroll
    for (int mt = 0; mt < 4; ++mt) {
      int r = mt * 16 + l16;
      int bo = r * ROWB + (((ks * 32 + lq * 8) * 2) ^ ((r & 7) << 4));
      a[mt] = *(const bf16x8*)(ldsb + bo);
    }
#pragma unroll
    for (int nt = 0; nt < 2; ++nt) {
      int coln = col0 + w * 32 + nt * 16 + l16;
      bf16x8 b = *(const bf16x8*)(B + (size_t)coln * K + ks * 32 + lq * 8);
#pragma unroll
      for (int mt = 0; mt < 4; ++mt)
        acc[mt][nt] = __builtin_amdgcn_mfma_f32_16x16x32_bf16(a[mt], b, acc[mt][nt], 0, 0, 0);
    }
  }
#pragma unroll
  for (int mt = 0; mt < 4; ++mt)
#pragma unroll
    for (int nt = 0; nt < 2; ++nt) {
      int coln = col0 + w * 32 + nt * 16 + l16;
#pragma unroll
      for (int j = 0; j < 4; ++j) {
        int r = row0 + mt * 16 + lq * 4 + j;
        float v = acc[mt][nt][j] + bf2f(XS[(size_t)r * HIDF + coln]);
        C[(size_t)r * HIDF + coln] = f2bf(fmaxf(v, 0.f));
      }
    }
}

// ---- fallback: one LSTM step per launch (round-6, known-correct) ---------
template <int F, bool T0>
__launch_bounds__(512, 8)
__global__ void k_step(const u16* __restrict__ hprev, // [N][F] node-major
                       const u16* __restrict__ XW,    // [N][4F] gate-interleaved
                       const u16* __restrict__ Whp,   // [4F][F]
                       const int* __restrict__ nbr,   // [N][DEG]
                       int t,
                       float* __restrict__ cT,        // [F][N] f32
                       u16* __restrict__ hnext) {     // [N][F] node-major
  constexpr int ROWB = 2 * F;
  constexpr int KS = F / 32;
  __shared__ __align__(16) u16 Alds[64 * F];
  __shared__ __align__(16) u16 tl[128 * 24];
  char* ldsb = (char*)Alds;
  const int tid = threadIdx.x;
  const int w = tid >> 6;
  const int lane = tid & 63;
  const int l16 = lane & 15, lq = lane >> 4;
  const int row0 = blockIdx.x * 64;
  const int col0 = blockIdx.y * 128;
  const int feb = row0 >> 2;
  const int n = col0 + w * 16 + l16;

  const int nb = nbr[(size_t)n * DEG + t];

  if constexpr (!T0) {
    constexpr int CH = F / 8;
    constexpr int RPI = 512 / CH;
#pragma unroll
    for (int it = 0; it < 64 / RPI; ++it) {
      int r = tid / CH + it * RPI;
      int ch = tid % CH;
      bf16x8 v = *(const bf16x8*)(Whp + (size_t)(row0 + r) * F + ch * 8);
      int bo = r * ROWB + ((ch * 16) ^ ((r & 7) << 4));
      *(bf16x8*)(ldsb + bo) = v;
    }
  }

  u16x4 xw[4];
  float cold[4];
#pragma unroll
  for (int mt = 0; mt < 4; ++mt) {
    xw[mt] = *(const u16x4*)(XW + (size_t)nb * (4 * F) + row0 + mt * 16 + lq * 4);
    if constexpr (!T0)
      cold[mt] = cT[(size_t)(feb + mt * 4 + lq) * N_NODES + n];
  }

  f32x4 acc[4];
#pragma unroll
  for (int mt = 0; mt < 4; ++mt)
#pragma unroll
    for (int j = 0; j < 4; ++j) acc[mt][j] = 0.f;

  if constexpr (!T0) {
    __syncthreads();
    const u16* hb = hprev + (size_t)n * F + lq * 8;
#pragma unroll
    for (int ks = 0; ks < KS; ++ks) {
      bf16x8 b = *(const bf16x8*)(hb + ks * 32);
      bf16x8 a[4];
#pragma unroll
      for (int mt = 0; mt < 4; ++mt) {
        int r = mt * 16 + l16;
        int bo = r * ROWB + (((ks * 32 + lq * 8) * 2) ^ ((r & 7) << 4));
        a[mt] = *(const bf16x8*)(ldsb + bo);
      }
#pragma unroll
      for (int mt = 0; mt < 4; ++mt)
        acc[mt] = __builtin_amdgcn_mfma_f32_16x16x32_bf16(a[mt], b, acc[mt], 0, 0, 0);
    }
  }

#pragma unroll
  for (int mt = 0; mt < 4; ++mt) {
    int fe = feb + mt * 4 + lq;
    float pi = acc[mt][0] + bf2f(xw[mt][0]);
    float pf = acc[mt][1] + bf2f(xw[mt][1]);
    float pg = acc[mt][2] + bf2f(xw[mt][2]);
    float po = acc[mt][3] + bf2f(xw[mt][3]);
    float cn;
    if constexpr (T0) cn = sigm(pi) * tanhfast(pg);
    else              cn = sigm(pf) * cold[mt] + sigm(pi) * tanhfast(pg);
    float hn = sigm(po) * tanhfast(cn);
    cT[(size_t)fe * N_NODES + n] = cn;
    tl[(w * 16 + l16) * 24 + mt * 4 + lq] = f2bf(hn);
  }
  __syncthreads();
  {
    int nloc = tid >> 2, q = tid & 3;
    u16x4 v = *(const u16x4*)&tl[nloc * 24 + q * 4];
    *(u16x4*)(hnext + (size_t)(col0 + nloc) * F + feb + q * 4) = v;
  }
}

// ---- grid-resident LSTM aggregation (cooperative) ------------------------
// Round-6 k_step math verbatim, made persistent: 512 blocks, each owns one
// 64-gate-row slice (rb) x IT node-groups of 128; Whp slice staged ONCE for
// all DEG steps; cell state c in REGISTERS (cst[IT][4], static idx) for all
// steps -> zero c memory traffic; grid.sync() between steps.
template <int F, int IT>
__launch_bounds__(512, 4)
__global__ void k_lstm(const u16* __restrict__ XW,   // [N][4F] gate-interleaved, bias folded
                       const u16* __restrict__ Whp,  // [4F][F]
                       const int* __restrict__ nbr,  // [N][DEG]
                       u16* __restrict__ hA,         // ping [N][F]
                       u16* __restrict__ hB) {       // pong [N][F]
  constexpr int ROWB = 2 * F;
  constexpr int KS = F / 32;
  constexpr int RBN = F / 16;              // (4F)/64 row-blocks
  __shared__ __align__(16) u16 Alds[64 * F];
  __shared__ __align__(16) u16 tl[128 * 24];
  char* ldsb = (char*)Alds;
  const int tid = threadIdx.x;
  const int w = tid >> 6;
  const int lane = tid & 63;
  const int l16 = lane & 15, lq = lane >> 4;
  const int rb = blockIdx.x % RBN;
  const int gset = blockIdx.x / RBN;
  const int row0 = rb * 64;
  const int feb = row0 >> 2;

  // stage Whp rows [row0, row0+64) once (read-only all steps)
  {
    constexpr int CH = F / 8;
    constexpr int RPI = 512 / CH;
#pragma unroll
    for (int it2 = 0; it2 < 64 / RPI; ++it2) {
      int r = tid / CH + it2 * RPI;
      int ch = tid % CH;
      bf16x8 v = *(const bf16x8*)(Whp + (size_t)(row0 + r) * F + ch * 8);
      int bo = r * ROWB + ((ch * 16) ^ ((r & 7) << 4));
      *(bf16x8*)(ldsb + bo) = v;
    }
  }

  float cst[IT][4];
#pragma unroll
  for (int i = 0; i < IT; ++i)
#pragma unroll
    for (int mt = 0; mt < 4; ++mt) cst[i][mt] = 0.f;

  __syncthreads();

  cgn::grid_group grid = cgn::this_grid();

#pragma unroll 1
  for (int t = 0; t < DEG; ++t) {
    const u16* __restrict__ hrd = (t & 1) ? hB : hA;
    u16* __restrict__ hwr = (t & 1) ? hA : hB;

#pragma unroll
    for (int i = 0; i < IT; ++i) {
      const int col0 = (gset * IT + i) * 128;
      const int n = col0 + w * 16 + l16;
      const int nb = nbr[(size_t)n * DEG + t];

      u16x4 xw[4];
#pragma unroll
      for (int mt = 0; mt < 4; ++mt)
        xw[mt] = *(const u16x4*)(XW + (size_t)nb * (4 * F) + row0 + mt * 16 + lq * 4);

      f32x4 acc[4];
#pragma unroll
      for (int mt = 0; mt < 4; ++mt)
#pragma unroll
        for (int j = 0; j < 4; ++j) acc[mt][j] = 0.f;

      if (t > 0) {
        const u16* hb = hrd + (size_t)n * F + lq * 8;
#pragma unroll
        for (int ks = 0; ks < KS; ++ks) {
          bf16x8 b = *(const bf16x8*)(hb + ks * 32);
          bf16x8 a[4];
#pragma unroll
          for (int mt = 0; mt < 4; ++mt) {
            int r = mt * 16 + l16;
            int bo = r * ROWB + (((ks * 32 + lq * 8) * 2) ^ ((r & 7) << 4));
            a[mt] = *(const bf16x8*)(ldsb + bo);
          }
#pragma unroll
          for (int mt = 0; mt < 4; ++mt)
            acc[mt] = __builtin_amdgcn_mfma_f32_16x16x32_bf16(a[mt], b, acc[mt], 0, 0, 0);
        }
      }

#pragma unroll
      for (int mt = 0; mt < 4; ++mt) {
        float pi = acc[mt][0] + bf2f(xw[mt][0]);
        float pf = acc[mt][1] + bf2f(xw[mt][1]);
        float pg = acc[mt][2] + bf2f(xw[mt][2]);
        float po = acc[mt][3] + bf2f(xw[mt][3]);
        float cn = sigm(pf) * cst[i][mt] + sigm(pi) * tanhfast(pg);
        cst[i][mt] = cn;
        float hn = sigm(po) * tanhfast(cn);
        tl[(w * 16 + l16) * 24 + mt * 4 + lq] = f2bf(hn);
      }
      __syncthreads();
      {
        int nloc = tid >> 2, q = tid & 3;
        u16x4 v = *(const u16x4*)&tl[nloc * 24 + q * 4];
        *(u16x4*)(hwr + (size_t)(col0 + nloc) * F + feb + q * 4) = v;
      }
      __syncthreads();
    }
    if (t + 1 < DEG) {
      __threadfence();
      grid.sync();
    }
  }
}

// ---- mean-pool per graph + classifier -----------------------------------
__global__ void k_pool(const u16* __restrict__ h2, const float* __restrict__ Wc,
                       const float* __restrict__ bc, float* __restrict__ out) {
  __shared__ float hg[HIDF];
  int g = blockIdx.x;
  int tid = threadIdx.x;
  float s = 0.0f;
  for (int i = 0; i < NPG; ++i) s += bf2f(h2[(size_t)(g * NPG + i) * HIDF + tid]);
  hg[tid] = s * (1.0f / NPG);
  __syncthreads();
  if (tid < OUT_F) {
    float o = bc[tid];
    for (int fe = 0; fe < HIDF; ++fe) o += hg[fe] * Wc[tid * HIDF + fe];
    out[g * OUT_F + tid] = o;
  }
}

// ---- launch -------------------------------------------------------------
extern "C" void kernel_launch(void* const* d_in, const int* in_sizes, int n_in,
                              void* d_out, int out_size, void* d_ws, size_t ws_size,
                              hipStream_t stream) {
  const float* x   = (const float*)d_in[0];
  const int*   nbr = (const int*)d_in[1];
  const float* Wi1 = (const float*)d_in[2];
  const float* Wh1 = (const float*)d_in[3];
  const float* bi1 = (const float*)d_in[4];
  const float* bh1 = (const float*)d_in[5];
  const float* Ws1 = (const float*)d_in[6];
  const float* Wn1 = (const float*)d_in[7];
  const float* b1  = (const float*)d_in[8];
  const float* Wi2 = (const float*)d_in[9];
  const float* Wh2 = (const float*)d_in[10];
  const float* bi2 = (const float*)d_in[11];
  const float* bh2 = (const float*)d_in[12];
  const float* Ws2 = (const float*)d_in[13];
  const float* Wn2 = (const float*)d_in[14];
  const float* b2  = (const float*)d_in[15];
  const float* Wc  = (const float*)d_in[16];
  const float* bc  = (const float*)d_in[17];
  float* out = (float*)d_out;

  char* ws = (char*)d_ws;
  const size_t MB = 1u << 20;
  // round-6 liveness-packed layout (c1/c2 used by the fallback path only):
  u16*   x16 = (u16*)(ws + 0);          //  8 MB, dead after XW1/XS1
  u16*   XW1 = (u16*)(ws + 8 * MB);     // 32 MB, dead after layer-1 steps
  u16*   XS1 = (u16*)(ws + 40 * MB);    // 16 MB; X2 in-place by comb1
  u16*   X2  = XS1;
  u16*   hA1 = (u16*)(ws + 56 * MB);    //  8 MB
  u16*   hB1 = (u16*)(ws + 64 * MB);    //  8 MB
  float* c1  = (float*)(ws + 72 * MB);  // 16 MB f32 [128][N]
  u16*   XW2 = (u16*)(ws + 88 * MB);    // 64 MB
  u16*   XS2 = (u16*)(ws + 64 * MB);    // 16 MB (over hB1+c1, dead after comb1)
  u16*   h2o = XS2;
  u16*   hA2 = (u16*)(ws + 0);          // 16 MB (over x16+XW1-start, dead)
  u16*   hB2 = (u16*)(ws + 16 * MB);    // 16 MB (over XW1, dead)
  float* c2  = (float*)(ws + 32 * MB);  // 32 MB (over XW1/X2/hA1, dead)
  char* wr = ws + 152 * MB;
  size_t off = 0;
  auto alloc = [&](size_t bytes) { void* p = wr + off; off += (bytes + 255) & ~(size_t)255; return p; };
  u16*   Wip1 = (u16*)alloc(512 * 128 * 2);
  u16*   Whp1 = (u16*)alloc(512 * 128 * 2);
  float* bwp1 = (float*)alloc(512 * 4);
  u16*   Bs1  = (u16*)alloc(256 * 128 * 2);
  u16*   Bn1  = (u16*)alloc(256 * 128 * 2);
  u16*   Wip2 = (u16*)alloc(1024 * 256 * 2);
  u16*   Whp2 = (u16*)alloc(1024 * 256 * 2);
  float* bwp2 = (float*)alloc(1024 * 4);
  u16*   Bs2  = (u16*)alloc(256 * 256 * 2);
  u16*   Bn2  = (u16*)alloc(256 * 256 * 2);

  k_prep_x<<<dim3(N_NODES * IN_F / 4 / 256), dim3(256), 0, stream>>>(x, x16, N_NODES * IN_F / 4);
  k_prep_wg<<<dim3(256), dim3(256), 0, stream>>>(Wi1, Wh1, bi1, bh1, Wip1, Whp1, bwp1, IN_F);
  k_prep_wg<<<dim3(1024), dim3(256), 0, stream>>>(Wi2, Wh2, bi2, bh2, Wip2, Whp2, bwp2, HIDF);
  k_prep_cast<<<dim3(128), dim3(256), 0, stream>>>(Ws1, Wn1, Bs1, Bn1, 256 * 128);
  k_prep_cast<<<dim3(256), dim3(256), 0, stream>>>(Ws2, Wn2, Bs2, Bn2, 256 * 256);

  // ---- layer 1 ----
  k_gemm<128, 512><<<dim3(N_NODES / 64, 4), dim3(256), 0, stream>>>(x16, Wip1, bwp1, XW1);
  k_gemm<128, 256><<<dim3(N_NODES / 64, 2), dim3(256), 0, stream>>>(x16, Bs1, b1, XS1);
  u16* h1fin;
  {
    const u16* xwp = XW1; const u16* whp = Whp1; const int* nb2 = nbr;
    u16* ha = hA1; u16* hb = hB1;
    void* args[] = {&xwp, &whp, &nb2, &ha, &hb};
    hipError_t ce = hipLaunchCooperativeKernel(
        reinterpret_cast<void*>(&k_lstm<IN_F, 4>), dim3(512), dim3(512), args, 0, stream);
    if (ce == hipSuccess) {
      h1fin = hA1;  // t=15 (odd) writes hA
    } else {
      (void)hipGetLastError();
      k_step<IN_F, true><<<dim3(8, N_NODES / 128), dim3(512), 0, stream>>>(
          hA1, XW1, Whp1, nbr, 0, c1, hA1);
      u16* hc = hA1; u16* hn = hB1;
      for (int t = 1; t < DEG; ++t) {
        k_step<IN_F, false><<<dim3(8, N_NODES / 128), dim3(512), 0, stream>>>(
            hc, XW1, Whp1, nbr, t, c1, hn);
        u16* tmp = hc; hc = hn; hn = tmp;
      }
      h1fin = hc;
    }
  }
  k_comb<128><<<dim3(N_NODES / 64, 2), dim3(256), 0, stream>>>(h1fin, Bn1, XS1, X2);

  // ---- layer 2 ----
  k_gemm<256, 1024><<<dim3(N_NODES / 64, 8), dim3(256), 0, stream>>>(X2, Wip2, bwp2, XW2);
  k_gemm<256, 256><<<dim3(N_NODES / 64, 2), dim3(256), 0, stream>>>(X2, Bs2, b2, XS2);
  u16* h2fin;
  {
    const u16* xwp = XW2; const u16* whp = Whp2; const int* nb2 = nbr;
    u16* ha = hA2; u16* hb = hB2;
    void* args[] = {&xwp, &whp, &nb2, &ha, &hb};
    hipError_t ce = hipLaunchCooperativeKernel(
        reinterpret_cast<void*>(&k_lstm<HIDF, 8>), dim3(512), dim3(512), args, 0, stream);
    if (ce == hipSuccess) {
      h2fin = hA2;
    } else {
      (void)hipGetLastError();
      k_step<HIDF, true><<<dim3(16, N_NODES / 128), dim3(512), 0, stream>>>(
          hA2, XW2, Whp2, nbr, 0, c2, hA2);
      u16* hc = hA2; u16* hn = hB2;
      for (int t = 1; t < DEG; ++t) {
        k_step<HIDF, false><<<dim3(16, N_NODES / 128), dim3(512), 0, stream>>>(
            hc, XW2, Whp2, nbr, t, c2, hn);
        u16* tmp = hc; hc = hn; hn = tmp;
      }
      h2fin = hc;
    }
  }
  k_comb<256><<<dim3(N_NODES / 64, 2), dim3(256), 0, stream>>>(h2fin, Bn2, XS2, h2o);

  k_pool<<<dim3(N_GRAPHS), dim3(256), 0, stream>>>(h2o, Wc, bc, out);
}

// Round 9
// 1851.209 us; speedup vs baseline: 2.9632x; 2.9632x over previous
//
#include <hip/hip_runtime.h>

#define N_NODES 32768
#define DEG 16
#define IN_F 128
#define HIDF 256
#define N_GRAPHS 256
#define NPG 128
#define OUT_F 16

typedef unsigned short u16;
typedef unsigned int u32;
typedef __bf16 bf16x8 __attribute__((ext_vector_type(8)));
typedef float f32x4 __attribute__((ext_vector_type(4)));
typedef u16 u16x4 __attribute__((ext_vector_type(4)));
typedef u16 u16x8 __attribute__((ext_vector_type(8)));

__device__ __forceinline__ u16 f2bf(float f) {
  union { float f; unsigned u; } v; v.f = f;
  return (u16)((v.u + 0x7FFFu + ((v.u >> 16) & 1u)) >> 16);
}
__device__ __forceinline__ float bf2f(u16 b) {
  union { unsigned u; float f; } v; v.u = ((unsigned)b) << 16;
  return v.f;
}
__device__ __forceinline__ float sigm(float x) { return 1.0f / (1.0f + __expf(-x)); }
__device__ __forceinline__ float tanhfast(float x) {
  float e = __expf(2.0f * x);
  return (e - 1.0f) / (e + 1.0f);
}

// ---- prep kernels -------------------------------------------------------

__global__ void k_prep_x(const float* __restrict__ x, u16* __restrict__ out, int n4) {
  int i = blockIdx.x * blockDim.x + threadIdx.x;
  if (i < n4) {
    float4 v = ((const float4*)x)[i];
    ushort4 o;
    o.x = f2bf(v.x); o.y = f2bf(v.y); o.z = f2bf(v.z); o.w = f2bf(v.w);
    ((ushort4*)out)[i] = o;
  }
}

// Gate-interleaved weight rows: p = fe*4 + gate (gate order i,f,g,o).
// So a 16x16 MFMA C-fragment's j index (rows lq*4+j) IS the gate index.
__global__ void k_prep_wg(const float* __restrict__ Wi, const float* __restrict__ Wh,
                          const float* __restrict__ bi, const float* __restrict__ bh,
                          u16* __restrict__ Wip, u16* __restrict__ Whp,
                          float* __restrict__ bwp, int F) {
  int total = 4 * F * F;
  for (int idx = blockIdx.x * blockDim.x + threadIdx.x; idx < total;
       idx += gridDim.x * blockDim.x) {
    int p = idx / F, k = idx % F;
    int fe = p >> 2, g = p & 3;
    int orig = g * F + fe;
    Wip[idx] = f2bf(Wi[orig * F + k]);
    Whp[idx] = f2bf(Wh[orig * F + k]);
    if (k == 0) bwp[p] = bi[orig] + bh[orig];
  }
}

__global__ void k_prep_cast(const float* __restrict__ Ws, const float* __restrict__ Wn,
                            u16* __restrict__ Bs, u16* __restrict__ Bn, int n) {
  int i = blockIdx.x * blockDim.x + threadIdx.x;
  if (i < n) { Bs[i] = f2bf(Ws[i]); Bn[i] = f2bf(Wn[i]); }
}

// ---- dense GEMM: C[M][NC] = bf16(A[M][K] @ B[NC][K]^T + bias) ------------
template <int K, int NC>
__launch_bounds__(256, 4)
__global__ void k_gemm(const u16* __restrict__ A, const u16* __restrict__ B,
                       const float* __restrict__ bias, u16* __restrict__ C) {
  constexpr int ROWB = 2 * K;
  __shared__ u16 lds[64 * K];
  char* ldsb = (char*)lds;
  const int tid = threadIdx.x;
  const int w = tid >> 6;
  const int lane = tid & 63;
  const int l16 = lane & 15, lq = lane >> 4;
  const int row0 = blockIdx.x * 64;
  const int col0 = blockIdx.y * 128;

  constexpr int CH = K / 8;
  constexpr int RPI = 256 / CH;
#pragma unroll
  for (int it = 0; it < 64 / RPI; ++it) {
    int r = tid / CH + it * RPI;
    int ch = tid % CH;
    bf16x8 v = *(const bf16x8*)(A + (size_t)(row0 + r) * K + ch * 8);
    int bo = r * ROWB + ((ch * 16) ^ ((r & 7) << 4));
    *(bf16x8*)(ldsb + bo) = v;
  }
  __syncthreads();

  f32x4 acc[4][2];
#pragma unroll
  for (int mt = 0; mt < 4; ++mt)
#pragma unroll
    for (int nt = 0; nt < 2; ++nt)
#pragma unroll
      for (int j = 0; j < 4; ++j) acc[mt][nt][j] = 0.f;

  for (int ks = 0; ks < K / 32; ++ks) {
    bf16x8 a[4];
#pragma unroll
    for (int mt = 0; mt < 4; ++mt) {
      int r = mt * 16 + l16;
      int bo = r * ROWB + (((ks * 32 + lq * 8) * 2) ^ ((r & 7) << 4));
      a[mt] = *(const bf16x8*)(ldsb + bo);
    }
#pragma unroll
    for (int nt = 0; nt < 2; ++nt) {
      int coln = col0 + w * 32 + nt * 16 + l16;
      bf16x8 b = *(const bf16x8*)(B + (size_t)coln * K + ks * 32 + lq * 8);
#pragma unroll
      for (int mt = 0; mt < 4; ++mt)
        acc[mt][nt] = __builtin_amdgcn_mfma_f32_16x16x32_bf16(a[mt], b, acc[mt][nt], 0, 0, 0);
    }
  }
#pragma unroll
  for (int mt = 0; mt < 4; ++mt)
#pragma unroll
    for (int nt = 0; nt < 2; ++nt) {
      int coln = col0 + w * 32 + nt * 16 + l16;
      float bb = bias[coln];
#pragma unroll
      for (int j = 0; j < 4; ++j) {
        int r = row0 + mt * 16 + lq * 4 + j;
        C[(size_t)r * NC + coln] = f2bf(acc[mt][nt][j] + bb);
      }
    }
}

// ---- combine GEMM: C[r][coln] = relu_bf16(XS[r][coln] + A[r]@B[coln]) ----
template <int K>
__launch_bounds__(256, 4)
__global__ void k_comb(const u16* __restrict__ A, const u16* __restrict__ B,
                       const u16* __restrict__ XS, u16* __restrict__ C) {
  constexpr int ROWB = 2 * K;
  __shared__ u16 lds[64 * K];
  char* ldsb = (char*)lds;
  const int tid = threadIdx.x;
  const int w = tid >> 6;
  const int lane = tid & 63;
  const int l16 = lane & 15, lq = lane >> 4;
  const int row0 = blockIdx.x * 64;
  const int col0 = blockIdx.y * 128;

  constexpr int CH = K / 8;
  constexpr int RPI = 256 / CH;
#pragma unroll
  for (int it = 0; it < 64 / RPI; ++it) {
    int r = tid / CH + it * RPI;
    int ch = tid % CH;
    bf16x8 v = *(const bf16x8*)(A + (size_t)(row0 + r) * K + ch * 8);
    int bo = r * ROWB + ((ch * 16) ^ ((r & 7) << 4));
    *(bf16x8*)(ldsb + bo) = v;
  }
  __syncthreads();

  f32x4 acc[4][2];
#pragma unroll
  for (int mt = 0; mt < 4; ++mt)
#pragma unroll
    for (int nt = 0; nt < 2; ++nt)
#pragma unroll
      for (int j = 0; j < 4; ++j) acc[mt][nt][j] = 0.f;

  for (int ks = 0; ks < K / 32; ++ks) {
    bf16x8 a[4];
#pragma unroll
    for (int mt = 0; mt < 4; ++mt) {
      int r = mt * 16 + l16;
      int bo = r * ROWB + (((ks * 32 + lq * 8) * 2) ^ ((r & 7) << 4));
      a[mt] = *(const bf16x8*)(ldsb + bo);
    }
#pragma unroll
    for (int nt = 0; nt < 2; ++nt) {
      int coln = col0 + w * 32 + nt * 16 + l16;
      bf16x8 b = *(const bf16x8*)(B + (size_t)coln * K + ks * 32 + lq * 8);
#pragma unroll
      for (int mt = 0; mt < 4; ++mt)
        acc[mt][nt] = __builtin_amdgcn_mfma_f32_16x16x32_bf16(a[mt], b, acc[mt][nt], 0, 0, 0);
    }
  }
#pragma unroll
  for (int mt = 0; mt < 4; ++mt)
#pragma unroll
    for (int nt = 0; nt < 2; ++nt) {
      int coln = col0 + w * 32 + nt * 16 + l16;
#pragma unroll
      for (int j = 0; j < 4; ++j) {
        int r = row0 + mt * 16 + lq * 4 + j;
        float v = acc[mt][nt][j] + bf2f(XS[(size_t)r * HIDF + coln]);
        C[(size_t)r * HIDF + coln] = f2bf(fmaxf(v, 0.f));
      }
    }
}

// ---- one LSTM step: gates = [Whp|Wip] @ [h ; x[nbr]] + b, fused cell -----
// Round-6 execution shape (BM=64 gate-rows x 128 nodes, 512 thr / 8 waves,
// one node per thread-column, 2 barriers) with the x-part fused into the
// GEMM: stage [Whp | Wip] rows (K2=2F) once per block, K-loop runs the
// h-half then the gathered-x half. Neighbor gather is the RAW x row (512B),
// 4x fewer unique bytes than the old precomputed-XW row; no XW GEMM at all.
// Bias is the accumulator init (j == gate). c state [F][N] f32.
// T0: h==0 -> h-half skipped entirely.
template <int F, bool T0>
__launch_bounds__(512, F == 128 ? 4 : 2)
__global__ void k_step(const u16* __restrict__ hprev, // [N][F] node-major
                       const u16* __restrict__ X,     // [N][F] gather source
                       const u16* __restrict__ Whp,   // [4F][F] gate-interleaved
                       const u16* __restrict__ Wip,   // [4F][F] gate-interleaved
                       const float* __restrict__ bwp, // [4F]
                       const int* __restrict__ nbr,   // [N][DEG]
                       int t,
                       float* __restrict__ cT,        // [F][N] f32
                       u16* __restrict__ hnext) {     // [N][F] node-major
  constexpr int K2 = 2 * F;
  constexpr int ROWB = 2 * K2;
  constexpr int KS = F / 32;
  __shared__ __align__(16) u16 Wst[64 * K2];
  __shared__ __align__(16) u16 tl[128 * 24];
  char* ldsb = (char*)Wst;
  const int tid = threadIdx.x;
  const int w = tid >> 6;
  const int lane = tid & 63;
  const int l16 = lane & 15, lq = lane >> 4;
  const int row0 = blockIdx.x * 64;
  const int col0 = blockIdx.y * 128;
  const int feb = row0 >> 2;
  const int n = col0 + w * 16 + l16;

  // issue neighbor id first (heads the longest chain)
  const int nb = nbr[(size_t)n * DEG + t];

  // stage [Whp | Wip] rows [row0, row0+64), swizzled
  {
    constexpr int CH = K2 / 8;
    constexpr int RPI = 512 / CH;
#pragma unroll
    for (int it = 0; it < 64 / RPI; ++it) {
      int r = tid / CH + it * RPI;
      int ch = tid % CH;
      const u16* src = (ch < CH / 2)
          ? (Whp + (size_t)(row0 + r) * F + ch * 8)
          : (Wip + (size_t)(row0 + r) * F + (ch - CH / 2) * 8);
      bf16x8 v = *(const bf16x8*)src;
      int bo = r * ROWB + ((ch * 16) ^ ((r & 7) << 4));
      *(bf16x8*)(ldsb + bo) = v;
    }
  }

  // c state, issued before the barrier
  float cold[4];
  if constexpr (!T0) {
#pragma unroll
    for (int mt = 0; mt < 4; ++mt)
      cold[mt] = cT[(size_t)(feb + mt * 4 + lq) * N_NODES + n];
  }

  // accumulator init = bias (j == gate index)
  f32x4 acc[4];
#pragma unroll
  for (int mt = 0; mt < 4; ++mt)
    acc[mt] = *(const f32x4*)(bwp + row0 + mt * 16 + lq * 4);

  __syncthreads();

  // h-half (skip at t=0)
  if constexpr (!T0) {
    const u16* hb = hprev + (size_t)n * F + lq * 8;
#pragma unroll
    for (int ks = 0; ks < KS; ++ks) {
      bf16x8 b = *(const bf16x8*)(hb + ks * 32);
      bf16x8 a[4];
#pragma unroll
      for (int mt = 0; mt < 4; ++mt) {
        int r = mt * 16 + l16;
        int bo = r * ROWB + (((ks * 32 + lq * 8) * 2) ^ ((r & 7) << 4));
        a[mt] = *(const bf16x8*)(ldsb + bo);
      }
#pragma unroll
      for (int mt = 0; mt < 4; ++mt)
        acc[mt] = __builtin_amdgcn_mfma_f32_16x16x32_bf16(a[mt], b, acc[mt], 0, 0, 0);
    }
  }
  // x-half: gathered neighbor feature row
  {
    const u16* xb = X + (size_t)nb * F + lq * 8;
#pragma unroll
    for (int ks = 0; ks < KS; ++ks) {
      bf16x8 b = *(const bf16x8*)(xb + ks * 32);
      bf16x8 a[4];
#pragma unroll
      for (int mt = 0; mt < 4; ++mt) {
        int r = mt * 16 + l16;
        int bo = r * ROWB + ((((F + ks * 32 + lq * 8)) * 2) ^ ((r & 7) << 4));
        a[mt] = *(const bf16x8*)(ldsb + bo);
      }
#pragma unroll
      for (int mt = 0; mt < 4; ++mt)
        acc[mt] = __builtin_amdgcn_mfma_f32_16x16x32_bf16(a[mt], b, acc[mt], 0, 0, 0);
    }
  }

  // fused LSTM cell update (in-lane: j = gate index i,f,g,o)
#pragma unroll
  for (int mt = 0; mt < 4; ++mt) {
    int fe = feb + mt * 4 + lq;
    float pi = acc[mt][0];
    float pf = acc[mt][1];
    float pg = acc[mt][2];
    float po = acc[mt][3];
    float cn;
    if constexpr (T0) cn = sigm(pi) * tanhfast(pg);
    else              cn = sigm(pf) * cold[mt] + sigm(pi) * tanhfast(pg);
    float hn = sigm(po) * tanhfast(cn);
    cT[(size_t)fe * N_NODES + n] = cn;
    tl[(w * 16 + l16) * 24 + mt * 4 + lq] = f2bf(hn);
  }
  __syncthreads();
  {
    int nloc = tid >> 2, q = tid & 3;
    u16x4 v = *(const u16x4*)&tl[nloc * 24 + q * 4];
    *(u16x4*)(hnext + (size_t)(col0 + nloc) * F + feb + q * 4) = v;
  }
}

// ---- mean-pool per graph + classifier -----------------------------------
__global__ void k_pool(const u16* __restrict__ h2, const float* __restrict__ Wc,
                       const float* __restrict__ bc, float* __restrict__ out) {
  __shared__ float hg[HIDF];
  int g = blockIdx.x;
  int tid = threadIdx.x;
  float s = 0.0f;
  for (int i = 0; i < NPG; ++i) s += bf2f(h2[(size_t)(g * NPG + i) * HIDF + tid]);
  hg[tid] = s * (1.0f / NPG);
  __syncthreads();
  if (tid < OUT_F) {
    float o = bc[tid];
    for (int fe = 0; fe < HIDF; ++fe) o += hg[fe] * Wc[tid * HIDF + fe];
    out[g * OUT_F + tid] = o;
  }
}

// ---- launch -------------------------------------------------------------
extern "C" void kernel_launch(void* const* d_in, const int* in_sizes, int n_in,
                              void* d_out, int out_size, void* d_ws, size_t ws_size,
                              hipStream_t stream) {
  const float* x   = (const float*)d_in[0];
  const int*   nbr = (const int*)d_in[1];
  const float* Wi1 = (const float*)d_in[2];
  const float* Wh1 = (const float*)d_in[3];
  const float* bi1 = (const float*)d_in[4];
  const float* bh1 = (const float*)d_in[5];
  const float* Ws1 = (const float*)d_in[6];
  const float* Wn1 = (const float*)d_in[7];
  const float* b1  = (const float*)d_in[8];
  const float* Wi2 = (const float*)d_in[9];
  const float* Wh2 = (const float*)d_in[10];
  const float* bi2 = (const float*)d_in[11];
  const float* bh2 = (const float*)d_in[12];
  const float* Ws2 = (const float*)d_in[13];
  const float* Wn2 = (const float*)d_in[14];
  const float* b2  = (const float*)d_in[15];
  const float* Wc  = (const float*)d_in[16];
  const float* bc  = (const float*)d_in[17];
  float* out = (float*)d_out;

  char* ws = (char*)d_ws;
  const size_t MB = 1u << 20;
  u16*   x16 = (u16*)(ws + 0);           //  8 MB
  u16*   XS1 = (u16*)(ws + 8 * MB);      // 16 MB; X2 in-place by comb1
  u16*   X2  = XS1;
  u16*   hA1 = (u16*)(ws + 24 * MB);     //  8 MB
  u16*   hB1 = (u16*)(ws + 32 * MB);     //  8 MB
  float* c1  = (float*)(ws + 40 * MB);   // 16 MB f32 [128][N]
  u16*   XS2 = (u16*)(ws + 56 * MB);     // 16 MB; h2o in-place by comb2
  u16*   h2o = XS2;
  u16*   hA2 = (u16*)(ws + 72 * MB);     // 16 MB
  u16*   hB2 = (u16*)(ws + 88 * MB);     // 16 MB
  float* c2  = (float*)(ws + 104 * MB);  // 32 MB f32 [256][N]
  char* wr = ws + 136 * MB;
  size_t off = 0;
  auto alloc = [&](size_t bytes) { void* p = wr + off; off += (bytes + 255) & ~(size_t)255; return p; };
  u16*   Wip1 = (u16*)alloc(512 * 128 * 2);
  u16*   Whp1 = (u16*)alloc(512 * 128 * 2);
  float* bwp1 = (float*)alloc(512 * 4);
  u16*   Bs1  = (u16*)alloc(256 * 128 * 2);
  u16*   Bn1  = (u16*)alloc(256 * 128 * 2);
  u16*   Wip2 = (u16*)alloc(1024 * 256 * 2);
  u16*   Whp2 = (u16*)alloc(1024 * 256 * 2);
  float* bwp2 = (float*)alloc(1024 * 4);
  u16*   Bs2  = (u16*)alloc(256 * 256 * 2);
  u16*   Bn2  = (u16*)alloc(256 * 256 * 2);

  k_prep_x<<<dim3(N_NODES * IN_F / 4 / 256), dim3(256), 0, stream>>>(x, x16, N_NODES * IN_F / 4);
  k_prep_wg<<<dim3(256), dim3(256), 0, stream>>>(Wi1, Wh1, bi1, bh1, Wip1, Whp1, bwp1, IN_F);
  k_prep_wg<<<dim3(1024), dim3(256), 0, stream>>>(Wi2, Wh2, bi2, bh2, Wip2, Whp2, bwp2, HIDF);
  k_prep_cast<<<dim3(128), dim3(256), 0, stream>>>(Ws1, Wn1, Bs1, Bn1, 256 * 128);
  k_prep_cast<<<dim3(256), dim3(256), 0, stream>>>(Ws2, Wn2, Bs2, Bn2, 256 * 256);

  // ---- layer 1 ----  (RBN = 4*IN_F/64 = 8 row-blocks)
  k_gemm<128, 256><<<dim3(N_NODES / 64, 2), dim3(256), 0, stream>>>(x16, Bs1, b1, XS1);
  {
    k_step<IN_F, true><<<dim3(8, N_NODES / 128), dim3(512), 0, stream>>>(
        hA1, x16, Whp1, Wip1, bwp1, nbr, 0, c1, hA1);
    u16* hc = hA1; u16* hn = hB1;
    for (int t = 1; t < DEG; ++t) {
      k_step<IN_F, false><<<dim3(8, N_NODES / 128), dim3(512), 0, stream>>>(
          hc, x16, Whp1, Wip1, bwp1, nbr, t, c1, hn);
      u16* tmp = hc; hc = hn; hn = tmp;
    }
    k_comb<128><<<dim3(N_NODES / 64, 2), dim3(256), 0, stream>>>(hc, Bn1, XS1, X2);
  }

  // ---- layer 2 ----  (RBN = 4*HIDF/64 = 16 row-blocks)
  k_gemm<256, 256><<<dim3(N_NODES / 64, 2), dim3(256), 0, stream>>>(X2, Bs2, b2, XS2);
  {
    k_step<HIDF, true><<<dim3(16, N_NODES / 128), dim3(512), 0, stream>>>(
        hA2, X2, Whp2, Wip2, bwp2, nbr, 0, c2, hA2);
    u16* hc = hA2; u16* hn = hB2;
    for (int t = 1; t < DEG; ++t) {
      k_step<HIDF, false><<<dim3(16, N_NODES / 128), dim3(512), 0, stream>>>(
          hc, X2, Whp2, Wip2, bwp2, nbr, t, c2, hn);
      u16* tmp = hc; hc = hn; hn = tmp;
    }
    k_comb<256><<<dim3(N_NODES / 64, 2), dim3(256), 0, stream>>>(hc, Bn2, XS2, h2o);
  }

  k_pool<<<dim3(N_GRAPHS), dim3(256), 0, stream>>>(h2o, Wc, bc, out);
}

// Round 10
// 1385.440 us; speedup vs baseline: 3.9594x; 1.3362x over previous
//
#include <hip/hip_runtime.h>

#define N_NODES 32768
#define DEG 16
#define IN_F 128
#define HIDF 256
#define N_GRAPHS 256
#define NPG 128
#define OUT_F 16

typedef unsigned short u16;
typedef unsigned int u32;
typedef __bf16 bf16x8 __attribute__((ext_vector_type(8)));
typedef float f32x4 __attribute__((ext_vector_type(4)));
typedef u16 u16x4 __attribute__((ext_vector_type(4)));
typedef u16 u16x8 __attribute__((ext_vector_type(8)));

__device__ __forceinline__ u16 f2bf(float f) {
  union { float f; unsigned u; } v; v.f = f;
  return (u16)((v.u + 0x7FFFu + ((v.u >> 16) & 1u)) >> 16);
}
__device__ __forceinline__ float bf2f(u16 b) {
  union { unsigned u; float f; } v; v.u = ((unsigned)b) << 16;
  return v.f;
}
__device__ __forceinline__ float sigm(float x) { return 1.0f / (1.0f + __expf(-x)); }
__device__ __forceinline__ float tanhfast(float x) {
  float e = __expf(2.0f * x);
  return (e - 1.0f) / (e + 1.0f);
}

// ---- prep kernels -------------------------------------------------------

__global__ void k_prep_x(const float* __restrict__ x, u16* __restrict__ out, int n4) {
  int i = blockIdx.x * blockDim.x + threadIdx.x;
  if (i < n4) {
    float4 v = ((const float4*)x)[i];
    ushort4 o;
    o.x = f2bf(v.x); o.y = f2bf(v.y); o.z = f2bf(v.z); o.w = f2bf(v.w);
    ((ushort4*)out)[i] = o;
  }
}

// Gate-interleaved weight rows: p = fe*4 + gate (gate order i,f,g,o).
// So a 16x16 MFMA C-fragment's j index (rows lq*4+j) IS the gate index.
__global__ void k_prep_wg(const float* __restrict__ Wi, const float* __restrict__ Wh,
                          const float* __restrict__ bi, const float* __restrict__ bh,
                          u16* __restrict__ Wip, u16* __restrict__ Whp,
                          float* __restrict__ bwp, int F) {
  int total = 4 * F * F;
  for (int idx = blockIdx.x * blockDim.x + threadIdx.x; idx < total;
       idx += gridDim.x * blockDim.x) {
    int p = idx / F, k = idx % F;
    int fe = p >> 2, g = p & 3;
    int orig = g * F + fe;
    Wip[idx] = f2bf(Wi[orig * F + k]);
    Whp[idx] = f2bf(Wh[orig * F + k]);
    if (k == 0) bwp[p] = bi[orig] + bh[orig];
  }
}

__global__ void k_prep_cast(const float* __restrict__ Ws, const float* __restrict__ Wn,
                            u16* __restrict__ Bs, u16* __restrict__ Bn, int n) {
  int i = blockIdx.x * blockDim.x + threadIdx.x;
  if (i < n) { Bs[i] = f2bf(Ws[i]); Bn[i] = f2bf(Wn[i]); }
}

// ---- dense GEMM: C[M][NC] = bf16(A[M][K] @ B[NC][K]^T + bias) ------------
template <int K, int NC>
__launch_bounds__(256, 4)
__global__ void k_gemm(const u16* __restrict__ A, const u16* __restrict__ B,
                       const float* __restrict__ bias, u16* __restrict__ C) {
  constexpr int ROWB = 2 * K;
  __shared__ u16 lds[64 * K];
  char* ldsb = (char*)lds;
  const int tid = threadIdx.x;
  const int w = tid >> 6;
  const int lane = tid & 63;
  const int l16 = lane & 15, lq = lane >> 4;
  const int row0 = blockIdx.x * 64;
  const int col0 = blockIdx.y * 128;

  constexpr int CH = K / 8;
  constexpr int RPI = 256 / CH;
#pragma unroll
  for (int it = 0; it < 64 / RPI; ++it) {
    int r = tid / CH + it * RPI;
    int ch = tid % CH;
    bf16x8 v = *(const bf16x8*)(A + (size_t)(row0 + r) * K + ch * 8);
    int bo = r * ROWB + ((ch * 16) ^ ((r & 7) << 4));
    *(bf16x8*)(ldsb + bo) = v;
  }
  __syncthreads();

  f32x4 acc[4][2];
#pragma unroll
  for (int mt = 0; mt < 4; ++mt)
#pragma unroll
    for (int nt = 0; nt < 2; ++nt)
#pragma unroll
      for (int j = 0; j < 4; ++j) acc[mt][nt][j] = 0.f;

  for (int ks = 0; ks < K / 32; ++ks) {
    bf16x8 a[4];
#pragma unroll
    for (int mt = 0; mt < 4; ++mt) {
      int r = mt * 16 + l16;
      int bo = r * ROWB + (((ks * 32 + lq * 8) * 2) ^ ((r & 7) << 4));
      a[mt] = *(const bf16x8*)(ldsb + bo);
    }
#pragma unroll
    for (int nt = 0; nt < 2; ++nt) {
      int coln = col0 + w * 32 + nt * 16 + l16;
      bf16x8 b = *(const bf16x8*)(B + (size_t)coln * K + ks * 32 + lq * 8);
#pragma unroll
      for (int mt = 0; mt < 4; ++mt)
        acc[mt][nt] = __builtin_amdgcn_mfma_f32_16x16x32_bf16(a[mt], b, acc[mt][nt], 0, 0, 0);
    }
  }
#pragma unroll
  for (int mt = 0; mt < 4; ++mt)
#pragma unroll
    for (int nt = 0; nt < 2; ++nt) {
      int coln = col0 + w * 32 + nt * 16 + l16;
      float bb = bias[coln];
#pragma unroll
      for (int j = 0; j < 4; ++j) {
        int r = row0 + mt * 16 + lq * 4 + j;
        C[(size_t)r * NC + coln] = f2bf(acc[mt][nt][j] + bb);
      }
    }
}

// ---- combine GEMM: C[r][coln] = relu_bf16(XS[r][coln] + A[r]@B[coln]) ----
template <int K>
__launch_bounds__(256, 4)
__global__ void k_comb(const u16* __restrict__ A, const u16* __restrict__ B,
                       const u16* __restrict__ XS, u16* __restrict__ C) {
  constexpr int ROWB = 2 * K;
  __shared__ u16 lds[64 * K];
  char* ldsb = (char*)lds;
  const int tid = threadIdx.x;
  const int w = tid >> 6;
  const int lane = tid & 63;
  const int l16 = lane & 15, lq = lane >> 4;
  const int row0 = blockIdx.x * 64;
  const int col0 = blockIdx.y * 128;

  constexpr int CH = K / 8;
  constexpr int RPI = 256 / CH;
#pragma unroll
  for (int it = 0; it < 64 / RPI; ++it) {
    int r = tid / CH + it * RPI;
    int ch = tid % CH;
    bf16x8 v = *(const bf16x8*)(A + (size_t)(row0 + r) * K + ch * 8);
    int bo = r * ROWB + ((ch * 16) ^ ((r & 7) << 4));
    *(bf16x8*)(ldsb + bo) = v;
  }
  __syncthreads();

  f32x4 acc[4][2];
#pragma unroll
  for (int mt = 0; mt < 4; ++mt)
#pragma unroll
    for (int nt = 0; nt < 2; ++nt)
#pragma unroll
      for (int j = 0; j < 4; ++j) acc[mt][nt][j] = 0.f;

  for (int ks = 0; ks < K / 32; ++ks) {
    bf16x8 a[4];
#pragma unroll
    for (int mt = 0; mt < 4; ++mt) {
      int r = mt * 16 + l16;
      int bo = r * ROWB + (((ks * 32 + lq * 8) * 2) ^ ((r & 7) << 4));
      a[mt] = *(const bf16x8*)(ldsb + bo);
    }
#pragma unroll
    for (int nt = 0; nt < 2; ++nt) {
      int coln = col0 + w * 32 + nt * 16 + l16;
      bf16x8 b = *(const bf16x8*)(B + (size_t)coln * K + ks * 32 + lq * 8);
#pragma unroll
      for (int mt = 0; mt < 4; ++mt)
        acc[mt][nt] = __builtin_amdgcn_mfma_f32_16x16x32_bf16(a[mt], b, acc[mt][nt], 0, 0, 0);
    }
  }
#pragma unroll
  for (int mt = 0; mt < 4; ++mt)
#pragma unroll
    for (int nt = 0; nt < 2; ++nt) {
      int coln = col0 + w * 32 + nt * 16 + l16;
#pragma unroll
      for (int j = 0; j < 4; ++j) {
        int r = row0 + mt * 16 + lq * 4 + j;
        float v = acc[mt][nt][j] + bf2f(XS[(size_t)r * HIDF + coln]);
        C[(size_t)r * HIDF + coln] = f2bf(fmaxf(v, 0.f));
      }
    }
}

// ---- one LSTM step as a dense GEMM + fused cell update -------------------
// Round-6 structure (proven 66.5us): BM=64 gate-rows x BN=128 nodes, 512
// thr / 8 waves, partitioned 128B XW gather (no request duplication),
// 2 barriers. Changes vs round 6:
//  - c state stored BF16 ([F][N] u16): -32 MB/step of L2-miss traffic.
//  - XCD-bijective swizzle: the RBN row-blocks of one node-group co-locate
//    on one XCD so their shared h/nbr requests hit the home L2.
template <int F, bool T0>
__launch_bounds__(512, 8)
__global__ void k_step(const u16* __restrict__ hprev, // [N][F] node-major
                       const u16* __restrict__ XW,    // [N][4F] gate-interleaved
                       const u16* __restrict__ Whp,   // [4F][F]
                       const int* __restrict__ nbr,   // [N][DEG]
                       int t,
                       u16* __restrict__ cT,          // [F][N] bf16
                       u16* __restrict__ hnext) {     // [N][F] node-major
  constexpr int ROWB = 2 * F;
  constexpr int KS = F / 32;
  constexpr int RBN = F / 16;   // gridDim.x
  __shared__ __align__(16) u16 Alds[64 * F];
  __shared__ __align__(16) u16 tl[128 * 24];
  char* ldsb = (char*)Alds;
  const int tid = threadIdx.x;
  const int w = tid >> 6;
  const int lane = tid & 63;
  const int l16 = lane & 15, lq = lane >> 4;

  // XCD-bijective swizzle: p%8 == XCD (round-robin dispatch); all RBN
  // row-blocks of node-group g land on XCD g%8. Bijection: total%8==0.
  const int p = blockIdx.x + RBN * blockIdx.y;
  const int s = p >> 3;
  const int rb = s % RBN;
  const int g = (p & 7) + 8 * (s / RBN);

  const int row0 = rb * 64;
  const int col0 = g * 128;
  const int feb = row0 >> 2;
  const int n = col0 + w * 16 + l16;

  const int nb = nbr[(size_t)n * DEG + t];

  if constexpr (!T0) {
    constexpr int CH = F / 8;
    constexpr int RPI = 512 / CH;
#pragma unroll
    for (int it = 0; it < 64 / RPI; ++it) {
      int r = tid / CH + it * RPI;
      int ch = tid % CH;
      bf16x8 v = *(const bf16x8*)(Whp + (size_t)(row0 + r) * F + ch * 8);
      int bo = r * ROWB + ((ch * 16) ^ ((r & 7) << 4));
      *(bf16x8*)(ldsb + bo) = v;
    }
  }

  u16x4 xw[4];
  float cold[4];
#pragma unroll
  for (int mt = 0; mt < 4; ++mt) {
    xw[mt] = *(const u16x4*)(XW + (size_t)nb * (4 * F) + row0 + mt * 16 + lq * 4);
    if constexpr (!T0)
      cold[mt] = bf2f(cT[(size_t)(feb + mt * 4 + lq) * N_NODES + n]);
  }

  f32x4 acc[4];
#pragma unroll
  for (int mt = 0; mt < 4; ++mt)
#pragma unroll
    for (int j = 0; j < 4; ++j) acc[mt][j] = 0.f;

  if constexpr (!T0) {
    __syncthreads();
    const u16* hb = hprev + (size_t)n * F + lq * 8;
#pragma unroll
    for (int ks = 0; ks < KS; ++ks) {
      bf16x8 b = *(const bf16x8*)(hb + ks * 32);
      bf16x8 a[4];
#pragma unroll
      for (int mt = 0; mt < 4; ++mt) {
        int r = mt * 16 + l16;
        int bo = r * ROWB + (((ks * 32 + lq * 8) * 2) ^ ((r & 7) << 4));
        a[mt] = *(const bf16x8*)(ldsb + bo);
      }
#pragma unroll
      for (int mt = 0; mt < 4; ++mt)
        acc[mt] = __builtin_amdgcn_mfma_f32_16x16x32_bf16(a[mt], b, acc[mt], 0, 0, 0);
    }
  }

#pragma unroll
  for (int mt = 0; mt < 4; ++mt) {
    int fe = feb + mt * 4 + lq;
    float pi = acc[mt][0] + bf2f(xw[mt][0]);
    float pf = acc[mt][1] + bf2f(xw[mt][1]);
    float pg = acc[mt][2] + bf2f(xw[mt][2]);
    float po = acc[mt][3] + bf2f(xw[mt][3]);
    float cn;
    if constexpr (T0) cn = sigm(pi) * tanhfast(pg);
    else              cn = sigm(pf) * cold[mt] + sigm(pi) * tanhfast(pg);
    float hn = sigm(po) * tanhfast(cn);
    cT[(size_t)fe * N_NODES + n] = f2bf(cn);
    tl[(w * 16 + l16) * 24 + mt * 4 + lq] = f2bf(hn);
  }
  __syncthreads();
  {
    int nloc = tid >> 2, q = tid & 3;
    u16x4 v = *(const u16x4*)&tl[nloc * 24 + q * 4];
    *(u16x4*)(hnext + (size_t)(col0 + nloc) * F + feb + q * 4) = v;
  }
}

// ---- mean-pool per graph + classifier -----------------------------------
__global__ void k_pool(const u16* __restrict__ h2, const float* __restrict__ Wc,
                       const float* __restrict__ bc, float* __restrict__ out) {
  __shared__ float hg[HIDF];
  int g = blockIdx.x;
  int tid = threadIdx.x;
  float s = 0.0f;
  for (int i = 0; i < NPG; ++i) s += bf2f(h2[(size_t)(g * NPG + i) * HIDF + tid]);
  hg[tid] = s * (1.0f / NPG);
  __syncthreads();
  if (tid < OUT_F) {
    float o = bc[tid];
    for (int fe = 0; fe < HIDF; ++fe) o += hg[fe] * Wc[tid * HIDF + fe];
    out[g * OUT_F + tid] = o;
  }
}

// ---- launch -------------------------------------------------------------
extern "C" void kernel_launch(void* const* d_in, const int* in_sizes, int n_in,
                              void* d_out, int out_size, void* d_ws, size_t ws_size,
                              hipStream_t stream) {
  const float* x   = (const float*)d_in[0];
  const int*   nbr = (const int*)d_in[1];
  const float* Wi1 = (const float*)d_in[2];
  const float* Wh1 = (const float*)d_in[3];
  const float* bi1 = (const float*)d_in[4];
  const float* bh1 = (const float*)d_in[5];
  const float* Ws1 = (const float*)d_in[6];
  const float* Wn1 = (const float*)d_in[7];
  const float* b1  = (const float*)d_in[8];
  const float* Wi2 = (const float*)d_in[9];
  const float* Wh2 = (const float*)d_in[10];
  const float* bi2 = (const float*)d_in[11];
  const float* bh2 = (const float*)d_in[12];
  const float* Ws2 = (const float*)d_in[13];
  const float* Wn2 = (const float*)d_in[14];
  const float* b2  = (const float*)d_in[15];
  const float* Wc  = (const float*)d_in[16];
  const float* bc  = (const float*)d_in[17];
  float* out = (float*)d_out;

  char* ws = (char*)d_ws;
  const size_t MB = 1u << 20;
  // liveness-packed (high-water 144 MB + weights):
  u16*   x16 = (u16*)(ws + 0);          //  8 MB, dead after XW1/XS1 gemms
  u16*   XW1 = (u16*)(ws + 8 * MB);     // 32 MB, dead after layer-1 steps
  u16*   XS1 = (u16*)(ws + 40 * MB);    // 16 MB; X2 in-place by comb1
  u16*   X2  = XS1;
  u16*   hA1 = (u16*)(ws + 56 * MB);    //  8 MB
  u16*   hB1 = (u16*)(ws + 64 * MB);    //  8 MB
  u16*   c1  = (u16*)(ws + 72 * MB);    //  8 MB bf16 [128][N]
  u16*   XW2 = (u16*)(ws + 80 * MB);    // 64 MB
  u16*   XS2 = (u16*)(ws + 0);          // 16 MB (over x16+XW1-head, dead); h2o in place
  u16*   h2o = XS2;
  u16*   hA2 = (u16*)(ws + 16 * MB);    // 16 MB (over XW1, dead)
  u16*   hB2 = (u16*)(ws + 32 * MB);    // 16 MB (over XW1-tail + X2, dead by t=1)
  u16*   c2  = (u16*)(ws + 56 * MB);    // 16 MB bf16 (over hA1/hB1/c1, dead after comb1)
  char* wr = ws + 144 * MB;
  size_t off = 0;
  auto alloc = [&](size_t bytes) { void* p = wr + off; off += (bytes + 255) & ~(size_t)255; return p; };
  u16*   Wip1 = (u16*)alloc(512 * 128 * 2);
  u16*   Whp1 = (u16*)alloc(512 * 128 * 2);
  float* bwp1 = (float*)alloc(512 * 4);
  u16*   Bs1  = (u16*)alloc(256 * 128 * 2);
  u16*   Bn1  = (u16*)alloc(256 * 128 * 2);
  u16*   Wip2 = (u16*)alloc(1024 * 256 * 2);
  u16*   Whp2 = (u16*)alloc(1024 * 256 * 2);
  float* bwp2 = (float*)alloc(1024 * 4);
  u16*   Bs2  = (u16*)alloc(256 * 256 * 2);
  u16*   Bn2  = (u16*)alloc(256 * 256 * 2);

  k_prep_x<<<dim3(N_NODES * IN_F / 4 / 256), dim3(256), 0, stream>>>(x, x16, N_NODES * IN_F / 4);
  k_prep_wg<<<dim3(256), dim3(256), 0, stream>>>(Wi1, Wh1, bi1, bh1, Wip1, Whp1, bwp1, IN_F);
  k_prep_wg<<<dim3(1024), dim3(256), 0, stream>>>(Wi2, Wh2, bi2, bh2, Wip2, Whp2, bwp2, HIDF);
  k_prep_cast<<<dim3(128), dim3(256), 0, stream>>>(Ws1, Wn1, Bs1, Bn1, 256 * 128);
  k_prep_cast<<<dim3(256), dim3(256), 0, stream>>>(Ws2, Wn2, Bs2, Bn2, 256 * 256);

  // ---- layer 1 ----
  k_gemm<128, 512><<<dim3(N_NODES / 64, 4), dim3(256), 0, stream>>>(x16, Wip1, bwp1, XW1);
  k_gemm<128, 256><<<dim3(N_NODES / 64, 2), dim3(256), 0, stream>>>(x16, Bs1, b1, XS1);
  {
    k_step<IN_F, true><<<dim3(8, N_NODES / 128), dim3(512), 0, stream>>>(
        hA1, XW1, Whp1, nbr, 0, c1, hA1);
    u16* hc = hA1; u16* hn = hB1;
    for (int t = 1; t < DEG; ++t) {
      k_step<IN_F, false><<<dim3(8, N_NODES / 128), dim3(512), 0, stream>>>(
          hc, XW1, Whp1, nbr, t, c1, hn);
      u16* tmp = hc; hc = hn; hn = tmp;
    }
    k_comb<128><<<dim3(N_NODES / 64, 2), dim3(256), 0, stream>>>(hc, Bn1, XS1, X2);
  }

  // ---- layer 2 ----
  k_gemm<256, 1024><<<dim3(N_NODES / 64, 8), dim3(256), 0, stream>>>(X2, Wip2, bwp2, XW2);
  k_gemm<256, 256><<<dim3(N_NODES / 64, 2), dim3(256), 0, stream>>>(X2, Bs2, b2, XS2);
  {
    k_step<HIDF, true><<<dim3(16, N_NODES / 128), dim3(512), 0, stream>>>(
        hA2, XW2, Whp2, nbr, 0, c2, hA2);
    u16* hc = hA2; u16* hn = hB2;
    for (int t = 1; t < DEG; ++t) {
      k_step<HIDF, false><<<dim3(16, N_NODES / 128), dim3(512), 0, stream>>>(
          hc, XW2, Whp2, nbr, t, c2, hn);
      u16* tmp = hc; hc = hn; hn = tmp;
    }
    k_comb<256><<<dim3(N_NODES / 64, 2), dim3(256), 0, stream>>>(hc, Bn2, XS2, h2o);
  }

  k_pool<<<dim3(N_GRAPHS), dim3(256), 0, stream>>>(h2o, Wc, bc, out);
}

// Round 11
// 1284.945 us; speedup vs baseline: 4.2691x; 1.0782x over previous
//
#include <hip/hip_runtime.h>

#define N_NODES 32768
#define DEG 16
#define IN_F 128
#define HIDF 256
#define N_GRAPHS 256
#define NPG 128
#define OUT_F 16

typedef unsigned short u16;
typedef unsigned int u32;
typedef __bf16 bf16x8 __attribute__((ext_vector_type(8)));
typedef float f32x4 __attribute__((ext_vector_type(4)));
typedef u16 u16x4 __attribute__((ext_vector_type(4)));
typedef u16 u16x8 __attribute__((ext_vector_type(8)));

__device__ __forceinline__ u16 f2bf(float f) {
  union { float f; unsigned u; } v; v.f = f;
  return (u16)((v.u + 0x7FFFu + ((v.u >> 16) & 1u)) >> 16);
}
__device__ __forceinline__ float bf2f(u16 b) {
  union { unsigned u; float f; } v; v.u = ((unsigned)b) << 16;
  return v.f;
}
__device__ __forceinline__ float sigm(float x) { return 1.0f / (1.0f + __expf(-x)); }
__device__ __forceinline__ float tanhfast(float x) {
  float e = __expf(2.0f * x);
  return (e - 1.0f) / (e + 1.0f);
}

// ---- prep kernels -------------------------------------------------------

__global__ void k_prep_x(const float* __restrict__ x, u16* __restrict__ out, int n4) {
  int i = blockIdx.x * blockDim.x + threadIdx.x;
  if (i < n4) {
    float4 v = ((const float4*)x)[i];
    ushort4 o;
    o.x = f2bf(v.x); o.y = f2bf(v.y); o.z = f2bf(v.z); o.w = f2bf(v.w);
    ((ushort4*)out)[i] = o;
  }
}

// Whp: gate-interleaved rows p = fe*4 + gate (MFMA C-fragment j == gate).
// Wip/bwp: additionally lq-major WITHIN each 64-row slice, so a k_step
// thread's 16 gather values (4 fe x 4 gates) are 32B contiguous:
//   new local q = lq*16 + mt*4 + gate  <->  old local = mt*16 + lq*4 + gate
__global__ void k_prep_wg(const float* __restrict__ Wi, const float* __restrict__ Wh,
                          const float* __restrict__ bi, const float* __restrict__ bh,
                          u16* __restrict__ Wip, u16* __restrict__ Whp,
                          float* __restrict__ bwp, int F) {
  int total = 4 * F * F;
  for (int idx = blockIdx.x * blockDim.x + threadIdx.x; idx < total;
       idx += gridDim.x * blockDim.x) {
    int p = idx / F, k = idx % F;
    {  // Whp: old order
      int fe = p >> 2, g = p & 3;
      int orig = g * F + fe;
      Whp[idx] = f2bf(Wh[orig * F + k]);
    }
    {  // Wip + bwp: lq-major slice order
      int base = p & ~63, local = p & 63;
      int lq = local >> 4, mt = (local >> 2) & 3, gate = local & 3;
      int oldp = base + mt * 16 + lq * 4 + gate;
      int fe = oldp >> 2, g = oldp & 3;
      int orig = g * F + fe;
      Wip[idx] = f2bf(Wi[orig * F + k]);
      if (k == 0) bwp[p] = bi[orig] + bh[orig];
    }
  }
}

__global__ void k_prep_cast(const float* __restrict__ Ws, const float* __restrict__ Wn,
                            u16* __restrict__ Bs, u16* __restrict__ Bn, int n) {
  int i = blockIdx.x * blockDim.x + threadIdx.x;
  if (i < n) { Bs[i] = f2bf(Ws[i]); Bn[i] = f2bf(Wn[i]); }
}

// ---- dense GEMM: C[M][NC] = bf16(A[M][K] @ B[NC][K]^T + bias) ------------
template <int K, int NC>
__launch_bounds__(256, 4)
__global__ void k_gemm(const u16* __restrict__ A, const u16* __restrict__ B,
                       const float* __restrict__ bias, u16* __restrict__ C) {
  constexpr int ROWB = 2 * K;
  __shared__ u16 lds[64 * K];
  char* ldsb = (char*)lds;
  const int tid = threadIdx.x;
  const int w = tid >> 6;
  const int lane = tid & 63;
  const int l16 = lane & 15, lq = lane >> 4;
  const int row0 = blockIdx.x * 64;
  const int col0 = blockIdx.y * 128;

  constexpr int CH = K / 8;
  constexpr int RPI = 256 / CH;
#pragma unroll
  for (int it = 0; it < 64 / RPI; ++it) {
    int r = tid / CH + it * RPI;
    int ch = tid % CH;
    bf16x8 v = *(const bf16x8*)(A + (size_t)(row0 + r) * K + ch * 8);
    int bo = r * ROWB + ((ch * 16) ^ ((r & 7) << 4));
    *(bf16x8*)(ldsb + bo) = v;
  }
  __syncthreads();

  f32x4 acc[4][2];
#pragma unroll
  for (int mt = 0; mt < 4; ++mt)
#pragma unroll
    for (int nt = 0; nt < 2; ++nt)
#pragma unroll
      for (int j = 0; j < 4; ++j) acc[mt][nt][j] = 0.f;

  for (int ks = 0; ks < K / 32; ++ks) {
    bf16x8 a[4];
#pragma unroll
    for (int mt = 0; mt < 4; ++mt) {
      int r = mt * 16 + l16;
      int bo = r * ROWB + (((ks * 32 + lq * 8) * 2) ^ ((r & 7) << 4));
      a[mt] = *(const bf16x8*)(ldsb + bo);
    }
#pragma unroll
    for (int nt = 0; nt < 2; ++nt) {
      int coln = col0 + w * 32 + nt * 16 + l16;
      bf16x8 b = *(const bf16x8*)(B + (size_t)coln * K + ks * 32 + lq * 8);
#pragma unroll
      for (int mt = 0; mt < 4; ++mt)
        acc[mt][nt] = __builtin_amdgcn_mfma_f32_16x16x32_bf16(a[mt], b, acc[mt][nt], 0, 0, 0);
    }
  }
#pragma unroll
  for (int mt = 0; mt < 4; ++mt)
#pragma unroll
    for (int nt = 0; nt < 2; ++nt) {
      int coln = col0 + w * 32 + nt * 16 + l16;
      float bb = bias[coln];
#pragma unroll
      for (int j = 0; j < 4; ++j) {
        int r = row0 + mt * 16 + lq * 4 + j;
        C[(size_t)r * NC + coln] = f2bf(acc[mt][nt][j] + bb);
      }
    }
}

// ---- combine GEMM: C[r][coln] = relu_bf16(XS[r][coln] + A[r]@B[coln]) ----
template <int K>
__launch_bounds__(256, 4)
__global__ void k_comb(const u16* __restrict__ A, const u16* __restrict__ B,
                       const u16* __restrict__ XS, u16* __restrict__ C) {
  constexpr int ROWB = 2 * K;
  __shared__ u16 lds[64 * K];
  char* ldsb = (char*)lds;
  const int tid = threadIdx.x;
  const int w = tid >> 6;
  const int lane = tid & 63;
  const int l16 = lane & 15, lq = lane >> 4;
  const int row0 = blockIdx.x * 64;
  const int col0 = blockIdx.y * 128;

  constexpr int CH = K / 8;
  constexpr int RPI = 256 / CH;
#pragma unroll
  for (int it = 0; it < 64 / RPI; ++it) {
    int r = tid / CH + it * RPI;
    int ch = tid % CH;
    bf16x8 v = *(const bf16x8*)(A + (size_t)(row0 + r) * K + ch * 8);
    int bo = r * ROWB + ((ch * 16) ^ ((r & 7) << 4));
    *(bf16x8*)(ldsb + bo) = v;
  }
  __syncthreads();

  f32x4 acc[4][2];
#pragma unroll
  for (int mt = 0; mt < 4; ++mt)
#pragma unroll
    for (int nt = 0; nt < 2; ++nt)
#pragma unroll
      for (int j = 0; j < 4; ++j) acc[mt][nt][j] = 0.f;

  for (int ks = 0; ks < K / 32; ++ks) {
    bf16x8 a[4];
#pragma unroll
    for (int mt = 0; mt < 4; ++mt) {
      int r = mt * 16 + l16;
      int bo = r * ROWB + (((ks * 32 + lq * 8) * 2) ^ ((r & 7) << 4));
      a[mt] = *(const bf16x8*)(ldsb + bo);
    }
#pragma unroll
    for (int nt = 0; nt < 2; ++nt) {
      int coln = col0 + w * 32 + nt * 16 + l16;
      bf16x8 b = *(const bf16x8*)(B + (size_t)coln * K + ks * 32 + lq * 8);
#pragma unroll
      for (int mt = 0; mt < 4; ++mt)
        acc[mt][nt] = __builtin_amdgcn_mfma_f32_16x16x32_bf16(a[mt], b, acc[mt][nt], 0, 0, 0);
    }
  }
#pragma unroll
  for (int mt = 0; mt < 4; ++mt)
#pragma unroll
    for (int nt = 0; nt < 2; ++nt) {
      int coln = col0 + w * 32 + nt * 16 + l16;
#pragma unroll
      for (int j = 0; j < 4; ++j) {
        int r = row0 + mt * 16 + lq * 4 + j;
        float v = acc[mt][nt][j] + bf2f(XS[(size_t)r * HIDF + coln]);
        C[(size_t)r * HIDF + coln] = f2bf(fmaxf(v, 0.f));
      }
    }
}

// ---- one LSTM step as a dense GEMM + fused cell update -------------------
// Wave-tile 64 rows x 32 nodes (BN=256/block): halves per-node LDS reads,
// staging traffic, block count, and per-node address VALU vs round 10.
// XW gather uses the lq-major slice layout: 2 x 16B per (thread, node),
// 4 lq lanes cover one full 64B line -> half the gather transactions.
// c state bf16 [F][N]; XCD-bijective swizzle keeps a node-group's RBN
// row-blocks on one XCD. 2 barriers. T0: skip staging + h-GEMM.
template <int F, bool T0>
__launch_bounds__(512, 4)
__global__ void k_step(const u16* __restrict__ hprev, // [N][F] node-major
                       const u16* __restrict__ XW,    // [N][4F] lq-major slices
                       const u16* __restrict__ Whp,   // [4F][F] old gate-order
                       const int* __restrict__ nbr,   // [N][DEG]
                       int t,
                       u16* __restrict__ cT,          // [F][N] bf16
                       u16* __restrict__ hnext) {     // [N][F] node-major
  constexpr int ROWB = 2 * F;
  constexpr int KS = F / 32;
  constexpr int RBN = F / 16;   // gridDim.x
  __shared__ __align__(16) u16 Alds[64 * F];
  __shared__ __align__(16) u16 tl[256 * 24];
  char* ldsb = (char*)Alds;
  const int tid = threadIdx.x;
  const int w = tid >> 6;
  const int lane = tid & 63;
  const int l16 = lane & 15, lq = lane >> 4;

  // XCD-bijective swizzle: all RBN row-blocks of node-group g share an XCD.
  const int p = blockIdx.x + RBN * blockIdx.y;
  const int s = p >> 3;
  const int rb = s % RBN;
  const int g = (p & 7) + 8 * (s / RBN);

  const int row0 = rb * 64;
  const int col0 = g * 256;
  const int feb = row0 >> 2;
  const int n0 = col0 + w * 32 + l16;
  const int n1 = n0 + 16;

  const int nb0 = nbr[(size_t)n0 * DEG + t];
  const int nb1 = nbr[(size_t)n1 * DEG + t];

  if constexpr (!T0) {
    constexpr int CH = F / 8;
    constexpr int RPI = 512 / CH;
#pragma unroll
    for (int it = 0; it < 64 / RPI; ++it) {
      int r = tid / CH + it * RPI;
      int ch = tid % CH;
      bf16x8 v = *(const bf16x8*)(Whp + (size_t)(row0 + r) * F + ch * 8);
      int bo = r * ROWB + ((ch * 16) ^ ((r & 7) << 4));
      *(bf16x8*)(ldsb + bo) = v;
    }
  }

  // XW gather: per node, this thread's 16 values are 32B contiguous
  u16x8 xwv[2][2];
  {
    const u16* b0 = XW + (size_t)nb0 * (4 * F) + row0 + lq * 16;
    const u16* b1 = XW + (size_t)nb1 * (4 * F) + row0 + lq * 16;
    xwv[0][0] = *(const u16x8*)(b0);
    xwv[0][1] = *(const u16x8*)(b0 + 8);
    xwv[1][0] = *(const u16x8*)(b1);
    xwv[1][1] = *(const u16x8*)(b1 + 8);
  }

  float cold[4][2];
  if constexpr (!T0) {
#pragma unroll
    for (int mt = 0; mt < 4; ++mt) {
      cold[mt][0] = bf2f(cT[(size_t)(feb + mt * 4 + lq) * N_NODES + n0]);
      cold[mt][1] = bf2f(cT[(size_t)(feb + mt * 4 + lq) * N_NODES + n1]);
    }
  }

  f32x4 acc[4][2];
#pragma unroll
  for (int mt = 0; mt < 4; ++mt)
#pragma unroll
    for (int nt = 0; nt < 2; ++nt)
#pragma unroll
      for (int j = 0; j < 4; ++j) acc[mt][nt][j] = 0.f;

  if constexpr (!T0) {
    __syncthreads();
    const u16* hb0 = hprev + (size_t)n0 * F + lq * 8;
    const u16* hb1 = hprev + (size_t)n1 * F + lq * 8;
#pragma unroll
    for (int ks = 0; ks < KS; ++ks) {
      bf16x8 b0 = *(const bf16x8*)(hb0 + ks * 32);
      bf16x8 b1 = *(const bf16x8*)(hb1 + ks * 32);
      bf16x8 a[4];
#pragma unroll
      for (int mt = 0; mt < 4; ++mt) {
        int r = mt * 16 + l16;
        int bo = r * ROWB + (((ks * 32 + lq * 8) * 2) ^ ((r & 7) << 4));
        a[mt] = *(const bf16x8*)(ldsb + bo);
      }
#pragma unroll
      for (int mt = 0; mt < 4; ++mt) {
        acc[mt][0] = __builtin_amdgcn_mfma_f32_16x16x32_bf16(a[mt], b0, acc[mt][0], 0, 0, 0);
        acc[mt][1] = __builtin_amdgcn_mfma_f32_16x16x32_bf16(a[mt], b1, acc[mt][1], 0, 0, 0);
      }
    }
  }

  // fused LSTM cell update (in-lane: j = gate index i,f,g,o)
#pragma unroll
  for (int mt = 0; mt < 4; ++mt) {
    int fe = feb + mt * 4 + lq;
#pragma unroll
    for (int nt = 0; nt < 2; ++nt) {
      int n = nt ? n1 : n0;
      float pi, pf, pg, po;
      if (mt < 2) {
        pi = acc[mt][nt][0] + bf2f(xwv[nt][0][(mt & 1) * 4 + 0]);
        pf = acc[mt][nt][1] + bf2f(xwv[nt][0][(mt & 1) * 4 + 1]);
        pg = acc[mt][nt][2] + bf2f(xwv[nt][0][(mt & 1) * 4 + 2]);
        po = acc[mt][nt][3] + bf2f(xwv[nt][0][(mt & 1) * 4 + 3]);
      } else {
        pi = acc[mt][nt][0] + bf2f(xwv[nt][1][(mt & 1) * 4 + 0]);
        pf = acc[mt][nt][1] + bf2f(xwv[nt][1][(mt & 1) * 4 + 1]);
        pg = acc[mt][nt][2] + bf2f(xwv[nt][1][(mt & 1) * 4 + 2]);
        po = acc[mt][nt][3] + bf2f(xwv[nt][1][(mt & 1) * 4 + 3]);
      }
      float cn;
      if constexpr (T0) cn = sigm(pi) * tanhfast(pg);
      else              cn = sigm(pf) * cold[mt][nt] + sigm(pi) * tanhfast(pg);
      float hn = sigm(po) * tanhfast(cn);
      cT[(size_t)fe * N_NODES + n] = f2bf(cn);
      tl[(w * 32 + nt * 16 + l16) * 24 + mt * 4 + lq] = f2bf(hn);
    }
  }
  __syncthreads();
  {
    int nloc = tid >> 1, q = tid & 1;
    u16x8 v = *(const u16x8*)&tl[nloc * 24 + q * 8];
    *(u16x8*)(hnext + (size_t)(col0 + nloc) * F + feb + q * 8) = v;
  }
}

// ---- mean-pool per graph + classifier -----------------------------------
__global__ void k_pool(const u16* __restrict__ h2, const float* __restrict__ Wc,
                       const float* __restrict__ bc, float* __restrict__ out) {
  __shared__ float hg[HIDF];
  int g = blockIdx.x;
  int tid = threadIdx.x;
  float s = 0.0f;
  for (int i = 0; i < NPG; ++i) s += bf2f(h2[(size_t)(g * NPG + i) * HIDF + tid]);
  hg[tid] = s * (1.0f / NPG);
  __syncthreads();
  if (tid < OUT_F) {
    float o = bc[tid];
    for (int fe = 0; fe < HIDF; ++fe) o += hg[fe] * Wc[tid * HIDF + fe];
    out[g * OUT_F + tid] = o;
  }
}

// ---- launch -------------------------------------------------------------
extern "C" void kernel_launch(void* const* d_in, const int* in_sizes, int n_in,
                              void* d_out, int out_size, void* d_ws, size_t ws_size,
                              hipStream_t stream) {
  const float* x   = (const float*)d_in[0];
  const int*   nbr = (const int*)d_in[1];
  const float* Wi1 = (const float*)d_in[2];
  const float* Wh1 = (const float*)d_in[3];
  const float* bi1 = (const float*)d_in[4];
  const float* bh1 = (const float*)d_in[5];
  const float* Ws1 = (const float*)d_in[6];
  const float* Wn1 = (const float*)d_in[7];
  const float* b1  = (const float*)d_in[8];
  const float* Wi2 = (const float*)d_in[9];
  const float* Wh2 = (const float*)d_in[10];
  const float* bi2 = (const float*)d_in[11];
  const float* bh2 = (const float*)d_in[12];
  const float* Ws2 = (const float*)d_in[13];
  const float* Wn2 = (const float*)d_in[14];
  const float* b2  = (const float*)d_in[15];
  const float* Wc  = (const float*)d_in[16];
  const float* bc  = (const float*)d_in[17];
  float* out = (float*)d_out;

  char* ws = (char*)d_ws;
  const size_t MB = 1u << 20;
  // liveness-packed (high-water 144 MB + weights):
  u16*   x16 = (u16*)(ws + 0);          //  8 MB, dead after XW1/XS1 gemms
  u16*   XW1 = (u16*)(ws + 8 * MB);     // 32 MB, dead after layer-1 steps
  u16*   XS1 = (u16*)(ws + 40 * MB);    // 16 MB; X2 in-place by comb1
  u16*   X2  = XS1;
  u16*   hA1 = (u16*)(ws + 56 * MB);    //  8 MB
  u16*   hB1 = (u16*)(ws + 64 * MB);    //  8 MB
  u16*   c1  = (u16*)(ws + 72 * MB);    //  8 MB bf16 [128][N]
  u16*   XW2 = (u16*)(ws + 80 * MB);    // 64 MB
  u16*   XS2 = (u16*)(ws + 0);          // 16 MB (over x16+XW1-head, dead); h2o in place
  u16*   h2o = XS2;
  u16*   hA2 = (u16*)(ws + 16 * MB);    // 16 MB (over XW1, dead)
  u16*   hB2 = (u16*)(ws + 32 * MB);    // 16 MB (over XW1-tail + X2, dead by t=1)
  u16*   c2  = (u16*)(ws + 56 * MB);    // 16 MB bf16 (over hA1/hB1/c1, dead after comb1)
  char* wr = ws + 144 * MB;
  size_t off = 0;
  auto alloc = [&](size_t bytes) { void* p = wr + off; off += (bytes + 255) & ~(size_t)255; return p; };
  u16*   Wip1 = (u16*)alloc(512 * 128 * 2);
  u16*   Whp1 = (u16*)alloc(512 * 128 * 2);
  float* bwp1 = (float*)alloc(512 * 4);
  u16*   Bs1  = (u16*)alloc(256 * 128 * 2);
  u16*   Bn1  = (u16*)alloc(256 * 128 * 2);
  u16*   Wip2 = (u16*)alloc(1024 * 256 * 2);
  u16*   Whp2 = (u16*)alloc(1024 * 256 * 2);
  float* bwp2 = (float*)alloc(1024 * 4);
  u16*   Bs2  = (u16*)alloc(256 * 256 * 2);
  u16*   Bn2  = (u16*)alloc(256 * 256 * 2);

  k_prep_x<<<dim3(N_NODES * IN_F / 4 / 256), dim3(256), 0, stream>>>(x, x16, N_NODES * IN_F / 4);
  k_prep_wg<<<dim3(256), dim3(256), 0, stream>>>(Wi1, Wh1, bi1, bh1, Wip1, Whp1, bwp1, IN_F);
  k_prep_wg<<<dim3(1024), dim3(256), 0, stream>>>(Wi2, Wh2, bi2, bh2, Wip2, Whp2, bwp2, HIDF);
  k_prep_cast<<<dim3(128), dim3(256), 0, stream>>>(Ws1, Wn1, Bs1, Bn1, 256 * 128);
  k_prep_cast<<<dim3(256), dim3(256), 0, stream>>>(Ws2, Wn2, Bs2, Bn2, 256 * 256);

  // ---- layer 1 ----  (RBN = 8, node-groups = 128)
  k_gemm<128, 512><<<dim3(N_NODES / 64, 4), dim3(256), 0, stream>>>(x16, Wip1, bwp1, XW1);
  k_gemm<128, 256><<<dim3(N_NODES / 64, 2), dim3(256), 0, stream>>>(x16, Bs1, b1, XS1);
  {
    k_step<IN_F, true><<<dim3(8, N_NODES / 256), dim3(512), 0, stream>>>(
        hA1, XW1, Whp1, nbr, 0, c1, hA1);
    u16* hc = hA1; u16* hn = hB1;
    for (int t = 1; t < DEG; ++t) {
      k_step<IN_F, false><<<dim3(8, N_NODES / 256), dim3(512), 0, stream>>>(
          hc, XW1, Whp1, nbr, t, c1, hn);
      u16* tmp = hc; hc = hn; hn = tmp;
    }
    k_comb<128><<<dim3(N_NODES / 64, 2), dim3(256), 0, stream>>>(hc, Bn1, XS1, X2);
  }

  // ---- layer 2 ----  (RBN = 16, node-groups = 128)
  k_gemm<256, 1024><<<dim3(N_NODES / 64, 8), dim3(256), 0, stream>>>(X2, Wip2, bwp2, XW2);
  k_gemm<256, 256><<<dim3(N_NODES / 64, 2), dim3(256), 0, stream>>>(X2, Bs2, b2, XS2);
  {
    k_step<HIDF, true><<<dim3(16, N_NODES / 256), dim3(512), 0, stream>>>(
        hA2, XW2, Whp2, nbr, 0, c2, hA2);
    u16* hc = hA2; u16* hn = hB2;
    for (int t = 1; t < DEG; ++t) {
      k_step<HIDF, false><<<dim3(16, N_NODES / 256), dim3(512), 0, stream>>>(
          hc, XW2, Whp2, nbr, t, c2, hn);
      u16* tmp = hc; hc = hn; hn = tmp;
    }
    k_comb<256><<<dim3(N_NODES / 64, 2), dim3(256), 0, stream>>>(hc, Bn2, XS2, h2o);
  }

  k_pool<<<dim3(N_GRAPHS), dim3(256), 0, stream>>>(h2o, Wc, bc, out);
}